// Round 5
// baseline (88.357 us; speedup 1.0000x reference)
//
#include <hip/hip_runtime.h>
#include <hip/hip_cooperative_groups.h>

namespace cg = cooperative_groups;

// SeMCA v6: single cooperative kernel, 400 blocks = (b,g) x 8 chunks.
// Fallback: R4's 3-kernel pipeline if cooperative launch is rejected.
#define BVO 28224   // 64*441 per-batch offset

// ================= cooperative single kernel =================
__global__ __launch_bounds__(256) void semca_coop(
    const float* __restrict__ x, const float* __restrict__ wk, const float* __restrict__ bk,
    const float* __restrict__ w1,
    const float* __restrict__ bn_gamma, const float* __restrict__ bn_beta,
    const float* __restrict__ bn_mean,  const float* __restrict__ bn_var,
    const float* __restrict__ w2, const float* __restrict__ b2,
    const float* __restrict__ wvw, const float* __restrict__ bv,
    float* __restrict__ att2c, float* __restrict__ pmz,
    float* __restrict__ out)
{
    cg::grid_group grid = cg::this_grid();

    int blk = blockIdx.x;            // 400 = bg*8 + ch
    int ch = blk & 7, bg = blk >> 3;
    int b = bg / 25, g = bg % 25;
    int ph = g / 5, pw = g % 5;
    int tid = threadIdx.x, lane = tid & 63, wv = tid >> 6;

    // LDS: 15808 floats = 61.75 KB  (2 blocks/CU)
    __shared__ float L[15808];
    float* k1u  = L;              // 1600 [c*25+p]      live A2..F
    float* att1 = L + 1600;       // 1600 [o][e]        live C..D
    float* red  = L + 3200;       // 256
    float* smM  = L + 3456;       // 64
    float* smR  = L + 3520;       // 64
    float* zone = L + 3584;       // 8128: xs (A..C), then a2s (E..F)
    float* wT   = L + 11712;      // 4096 [cv][e]
    float* xs   = zone;           // 1600 [u=25c+p]
    float* a2s  = zone;           // 8128

    // ---- A1: gather x at this (b,g)'s 25 pixels ----
    for (int u = tid; u < 1600; u += 256) {
        int c = u / 25, p = u - 25*c;
        int row = 5*(p/5) + ph, col = 5*(p%5) + pw;
        xs[u] = (row < 21 && col < 21) ? x[b*BVO + c*441 + row*21 + col] : 0.f;
    }
    __syncthreads();

    // ---- A2: k1 at the 25 pixels (depthwise conv over channel axis) ----
    for (int k = 0; k < 7; ++k) {
        int p = wv + 4*k;
        if (p >= 25) break;                       // wave-uniform
        int row = 5*(p/5) + ph, col = 5*(p%5) + pw;
        float acc = 0.f;
        if (row < 21 && col < 21) {               // wave-uniform
            int d = row*21 + col;
            const float* wkp = wk + d*441 + 220 - lane;
            float a0 = 0.f, a1 = 0.f;
            #pragma unroll
            for (int cp = 0; cp < 64; cp += 2) {
                a0 += xs[25*cp + p]     * wkp[cp];
                a1 += xs[25*(cp+1) + p] * wkp[cp+1];
            }
            acc = bk[d] + a0 + a1;
        }
        k1u[lane*25 + p] = acc;                   // lane = channel c
    }
    __syncthreads();

    // ---- C: att1[o][e] = relu(BN(w1[g] @ kq)) ----
    {
        float kq[50];
        #pragma unroll
        for (int m = 0; m < 25; ++m) kq[m] = xs[m*64 + lane];
        #pragma unroll
        for (int m = 0; m < 25; ++m) kq[25+m] = k1u[m*64 + lane];
        const float* w1g = w1 + g*1250;
        for (int k = 0; k < 7; ++k) {
            int o = wv + 4*k;
            if (o >= 25) break;                   // wave-uniform
            const float* wp = w1g + o*50;         // uniform -> s_loads
            float a0 = 0.f, a1 = 0.f;
            #pragma unroll
            for (int m = 0; m < 50; m += 2) { a0 += wp[m]*kq[m]; a1 += wp[m+1]*kq[m+1]; }
            float acc = a0 + a1;
            float inv = bn_gamma[g*25+o] * rsqrtf(bn_var[g*25+o] + 1e-5f);
            acc = (acc - bn_mean[g*25+o]) * inv + bn_beta[g*25+o];
            att1[o*64 + lane] = fmaxf(acc, 0.f);
        }
    }
    __syncthreads();

    // ---- D: this chunk's 56 att2 rows + chunk softmax stats ----
    float a1r[25];
    #pragma unroll
    for (int i = 0; i < 25; ++i) a1r[i] = att1[i*64 + lane];

    {
        int base = __builtin_amdgcn_readfirstlane(56*ch + 14*wv);
        const float* w2g = w2 + g*11025 + base*25;  // uniform -> s_loads
        const float* b2g = b2 + g*441 + base;
        float vals[14];
        #pragma unroll
        for (int j = 0; j < 14; ++j) {
            int r = base + j;
            if (r < 441) {
                const float* wp = w2g + j*25;
                float a0 = 0.f, a1 = 0.f;
                #pragma unroll
                for (int i = 0; i < 24; i += 2) { a0 += wp[i]*a1r[i]; a1 += wp[i+1]*a1r[i+1]; }
                vals[j] = b2g[j] + a0 + a1 + wp[24]*a1r[24];
                if (r >= 157 && r < 284)
                    att2c[(bg*127 + (r-157))*64 + lane] = vals[j];
            } else {
                vals[j] = -1e30f;
            }
        }
        float mx = vals[0];
        #pragma unroll
        for (int j = 1; j < 14; ++j) mx = fmaxf(mx, vals[j]);
        red[wv*64 + lane] = mx;
        __syncthreads();
        float M4 = fmaxf(fmaxf(red[0*64+lane], red[1*64+lane]),
                         fmaxf(red[2*64+lane], red[3*64+lane]));
        float z = 0.f;
        #pragma unroll
        for (int j = 0; j < 14; ++j) z += __expf(vals[j] - M4);
        __syncthreads();
        red[wv*64 + lane] = z;
        __syncthreads();
        if (wv == 0) {
            float Z = red[0*64+lane] + red[1*64+lane] + red[2*64+lane] + red[3*64+lane];
            pmz[blk*128 + lane]      = M4;
            pmz[blk*128 + 64 + lane] = Z;
        }
    }

    grid.sync();

    // ---- E: combine stats + build window weights wT[cv][e] ----
    for (int i = tid; i < 8128; i += 256) a2s[i] = att2c[bg*8128 + i];
    if (tid < 64) {
        float M = -1e30f;
        #pragma unroll
        for (int c = 0; c < 8; ++c) M = fmaxf(M, pmz[(bg*8+c)*128 + tid]);
        float Z = 0.f;
        #pragma unroll
        for (int c = 0; c < 8; ++c)
            Z += pmz[(bg*8+c)*128 + 64 + tid] * __expf(pmz[(bg*8+c)*128 + tid] - M);
        smM[tid] = M;
        smR[tid] = 1.f / Z;
    }
    __syncthreads();
    {
        float Me = smM[lane], Re = smR[lane];
        #pragma unroll
        for (int k = 0; k < 16; ++k) {
            int cv = wv + 4*k;
            // diagonal read: addr = (cv+63-lane)*64 + lane -> bank = lane%32, conflict-free
            wT[cv*64 + lane] = __expf(a2s[(cv + 63 - lane)*64 + lane] - Me) * Re;
        }
    }
    __syncthreads();

    // ---- F: this chunk's output pixels (p = ch + 8*wv), v-conv + dot + residual ----
    int y0 = (ph + 3) % 5, x0 = (pw + 3) % 5;
    int nx = (21 - x0 + 4) / 5, ny = (21 - y0 + 4) / 5;
    int npix = ny * nx;
    int p = ch + 8*wv;                             // covers 0..31 across (ch,wv)
    if (p < npix) {                                // wave-uniform
        int yy = y0 + 5*(p / nx), xx = x0 + 5*(p % nx);
        float vt = 0.f;
        if (yy >= 2 && xx >= 2) {                  // wave-uniform
            int vy = yy - 2, vx = xx - 2;
            float vval = bv[lane];
            const float* xp = x + b*BVO + lane*441;
            #pragma unroll
            for (int ky = 0; ky < 3; ++ky) {
                int r2 = vy + ky - 1;
                if (r2 < 0 || r2 >= 21) continue;
                #pragma unroll
                for (int kx = 0; kx < 3; ++kx) {
                    int c2 = vx + kx - 1;
                    if (c2 < 0 || c2 >= 21) continue;
                    vval += xp[r2*21 + c2] * wvw[lane*9 + ky*3 + kx];
                }
            }
            #pragma unroll
            for (int cv = 0; cv < 64; ++cv) {
                float s = __uint_as_float(__builtin_amdgcn_readlane(__float_as_uint(vval), cv));
                vt += s * wT[cv*64 + lane];
            }
        }
        int pk = ((yy + 2 - ph) / 5) * 5 + ((xx + 2 - pw) / 5);
        out[b*BVO + lane*441 + yy*21 + xx] = k1u[lane*25 + pk] + vt;
    }
}

// ================= fallback: R4's 3-kernel pipeline =================
__global__ __launch_bounds__(256) void kA(
    const float* __restrict__ x, const float* __restrict__ wk, const float* __restrict__ bk,
    const float* __restrict__ w1,
    const float* __restrict__ bn_gamma, const float* __restrict__ bn_beta,
    const float* __restrict__ bn_mean,  const float* __restrict__ bn_var,
    float* __restrict__ k1g, float* __restrict__ att1g)
{
    int blk = blockIdx.x;
    int b = blk / 25, g = blk % 25;
    int ph = g / 5, pw = g % 5;
    int tid = threadIdx.x, lane = tid & 63, wv = tid >> 6;
    __shared__ float xs[1600];
    __shared__ float k1u[1600];
    for (int u = tid; u < 1600; u += 256) {
        int c = u / 25, p = u - 25 * c;
        int row = 5*(p/5) + ph, col = 5*(p%5) + pw;
        xs[u] = (row < 21 && col < 21) ? x[b*BVO + c*441 + row*21 + col] : 0.f;
    }
    __syncthreads();
    for (int k = 0; k < 7; ++k) {
        int p = wv + 4*k;
        if (p >= 25) break;
        int row = 5*(p/5) + ph, col = 5*(p%5) + pw;
        float acc = 0.f;
        if (row < 21 && col < 21) {
            int d = row*21 + col;
            const float* wkp = wk + d*441 + 220 - lane;
            float a0 = 0.f, a1 = 0.f;
            #pragma unroll
            for (int cp = 0; cp < 64; cp += 2) {
                a0 += xs[25*cp + p]     * wkp[cp];
                a1 += xs[25*(cp+1) + p] * wkp[cp+1];
            }
            acc = bk[d] + a0 + a1;
        }
        k1u[lane*25 + p] = acc;
        k1g[blk*1600 + p*64 + lane] = acc;
    }
    __syncthreads();
    float kq[50];
    #pragma unroll
    for (int m = 0; m < 25; ++m) kq[m] = xs[m*64 + lane];
    #pragma unroll
    for (int m = 0; m < 25; ++m) kq[25+m] = k1u[m*64 + lane];
    const float* w1g = w1 + g*1250;
    for (int k = 0; k < 7; ++k) {
        int o = wv + 4*k;
        if (o >= 25) break;
        const float* wp = w1g + o*50;
        float a0 = 0.f, a1 = 0.f;
        #pragma unroll
        for (int m = 0; m < 50; m += 2) { a0 += wp[m]*kq[m]; a1 += wp[m+1]*kq[m+1]; }
        float acc = a0 + a1;
        float inv = bn_gamma[g*25+o] * rsqrtf(bn_var[g*25+o] + 1e-5f);
        acc = (acc - bn_mean[g*25+o]) * inv + bn_beta[g*25+o];
        att1g[blk*1600 + o*64 + lane] = fmaxf(acc, 0.f);
    }
}

__global__ __launch_bounds__(256) void kB(
    const float* __restrict__ att1g, const float* __restrict__ w2,
    const float* __restrict__ b2,
    float* __restrict__ att2c, float* __restrict__ pm, float* __restrict__ pz)
{
    int blk = blockIdx.x;
    int ch = blk & 7, bg = blk >> 3;
    int g  = bg % 25;
    int tid = threadIdx.x, lane = tid & 63, wv = tid >> 6;
    float a1r[25];
    #pragma unroll
    for (int i = 0; i < 25; ++i) a1r[i] = att1g[bg*1600 + i*64 + lane];
    int base = __builtin_amdgcn_readfirstlane(56*ch + 14*wv);
    const float* w2g = w2 + g*11025 + base*25;
    const float* b2g = b2 + g*441 + base;
    float vals[14];
    #pragma unroll
    for (int j = 0; j < 14; ++j) {
        int r = base + j;
        if (r < 441) {
            const float* wp = w2g + j*25;
            float a0 = 0.f, a1 = 0.f;
            #pragma unroll
            for (int i = 0; i < 24; i += 2) { a0 += wp[i]*a1r[i]; a1 += wp[i+1]*a1r[i+1]; }
            vals[j] = b2g[j] + a0 + a1 + wp[24]*a1r[24];
            if (r >= 157 && r < 284)
                att2c[(bg*127 + (r-157))*64 + lane] = vals[j];
        } else {
            vals[j] = -1e30f;
        }
    }
    float mx = vals[0];
    #pragma unroll
    for (int j = 1; j < 14; ++j) mx = fmaxf(mx, vals[j]);
    __shared__ float red[4][64];
    red[wv][lane] = mx;
    __syncthreads();
    float M = fmaxf(fmaxf(red[0][lane], red[1][lane]), fmaxf(red[2][lane], red[3][lane]));
    float z = 0.f;
    #pragma unroll
    for (int j = 0; j < 14; ++j) z += __expf(vals[j] - M);
    __syncthreads();
    red[wv][lane] = z;
    __syncthreads();
    if (wv == 0) {
        float Z = red[0][lane] + red[1][lane] + red[2][lane] + red[3][lane];
        pm[blk*64 + lane] = M;
        pz[blk*64 + lane] = Z;
    }
}

__global__ __launch_bounds__(256) void kC(
    const float* __restrict__ x, const float* __restrict__ wvw, const float* __restrict__ bv,
    const float* __restrict__ k1g, const float* __restrict__ att2c,
    const float* __restrict__ pm, const float* __restrict__ pz,
    float* __restrict__ out)
{
    int blk = blockIdx.x;
    int b = blk / 25, g = blk % 25;
    int ph = g / 5, pw = g % 5;
    int tid = threadIdx.x, lane = tid & 63, wv = tid >> 6;
    __shared__ float a2s[8128];
    __shared__ float wT[4096];
    __shared__ float smM[64], smR[64];
    for (int i = tid; i < 8128; i += 256) a2s[i] = att2c[blk*8128 + i];
    if (tid < 64) {
        float M = -1e30f;
        #pragma unroll
        for (int c = 0; c < 8; ++c) M = fmaxf(M, pm[(blk*8 + c)*64 + tid]);
        float Z = 0.f;
        #pragma unroll
        for (int c = 0; c < 8; ++c)
            Z += pz[(blk*8 + c)*64 + tid] * __expf(pm[(blk*8 + c)*64 + tid] - M);
        smM[tid] = M;
        smR[tid] = 1.f / Z;
    }
    __syncthreads();
    float Me = smM[lane], Re = smR[lane];
    #pragma unroll
    for (int k = 0; k < 16; ++k) {
        int cv = wv + 4*k;
        wT[cv*64 + lane] = __expf(a2s[(cv + 63 - lane)*64 + lane] - Me) * Re;
    }
    __syncthreads();
    int y0 = (ph + 3) % 5, x0 = (pw + 3) % 5;
    int ny = (21 - y0 + 4) / 5, nx = (21 - x0 + 4) / 5;
    int npix = ny * nx;
    for (int k = 0; k < 7; ++k) {
        int p = wv + 4*k;
        if (p >= npix) break;
        int yy = y0 + 5*(p / nx), xx = x0 + 5*(p % nx);
        float vt = 0.f;
        if (yy >= 2 && xx >= 2) {
            int vy = yy - 2, vx = xx - 2;
            float vval = bv[lane];
            const float* xp = x + b*BVO + lane*441;
            #pragma unroll
            for (int ky = 0; ky < 3; ++ky) {
                int r2 = vy + ky - 1;
                if (r2 < 0 || r2 >= 21) continue;
                #pragma unroll
                for (int kx = 0; kx < 3; ++kx) {
                    int c2 = vx + kx - 1;
                    if (c2 < 0 || c2 >= 21) continue;
                    vval += xp[r2*21 + c2] * wvw[lane*9 + ky*3 + kx];
                }
            }
            #pragma unroll
            for (int cv = 0; cv < 64; ++cv) {
                float s = __uint_as_float(__builtin_amdgcn_readlane(__float_as_uint(vval), cv));
                vt += s * wT[cv*64 + lane];
            }
        }
        int pk = ((yy + 2 - ph) / 5) * 5 + ((xx + 2 - pw) / 5);
        float kt = k1g[blk*1600 + pk*64 + lane];
        out[b*BVO + lane*441 + yy*21 + xx] = kt + vt;
    }
}

extern "C" void kernel_launch(void* const* d_in, const int* in_sizes, int n_in,
                              void* d_out, int out_size, void* d_ws, size_t ws_size,
                              hipStream_t stream) {
    const float* x        = (const float*)d_in[0];
    const float* wk       = (const float*)d_in[1];
    const float* bk       = (const float*)d_in[2];
    const float* w1       = (const float*)d_in[3];
    const float* bn_gamma = (const float*)d_in[4];
    const float* bn_beta  = (const float*)d_in[5];
    const float* bn_mean  = (const float*)d_in[6];
    const float* bn_var   = (const float*)d_in[7];
    const float* w2       = (const float*)d_in[8];
    const float* b2       = (const float*)d_in[9];
    const float* wv       = (const float*)d_in[10];
    const float* bv       = (const float*)d_in[11];

    float* out   = (float*)d_out;
    float* k1g   = (float*)d_ws;        // 80000   (fallback)
    float* att1g = k1g + 80000;         // 80000   (fallback)
    float* att2c = att1g + 80000;       // 406400  (shared)
    float* pm    = att2c + 406400;      // 25600   (fallback)
    float* pz    = pm + 25600;          // 25600   (fallback)
    float* pmz   = pz + 25600;          // 51200   (coop)

    void* args[] = { (void*)&x, (void*)&wk, (void*)&bk, (void*)&w1,
                     (void*)&bn_gamma, (void*)&bn_beta, (void*)&bn_mean, (void*)&bn_var,
                     (void*)&w2, (void*)&b2, (void*)&wv, (void*)&bv,
                     (void*)&att2c, (void*)&pmz, (void*)&out };
    hipError_t err = hipLaunchCooperativeKernel((const void*)semca_coop,
                                                dim3(400), dim3(256), args, 0, stream);
    if (err != hipSuccess) {
        (void)hipGetLastError();        // clear sticky error, use fallback path
        hipLaunchKernelGGL(kA, dim3(50), dim3(256), 0, stream,
                           x, wk, bk, w1, bn_gamma, bn_beta, bn_mean, bn_var, k1g, att1g);
        hipLaunchKernelGGL(kB, dim3(400), dim3(256), 0, stream,
                           att1g, w2, b2, att2c, pm, pz);
        hipLaunchKernelGGL(kC, dim3(50), dim3(256), 0, stream,
                           x, wv, bv, k1g, att2c, pm, pz, out);
    }
}

// Round 6
// 37.540 us; speedup vs baseline: 2.3537x; 2.3537x over previous
//
#include <hip/hip_runtime.h>

// SeMCA v7: 2-kernel pipeline.
// k1k: 400 blocks = (b,g) x 8 chunks. Each block recomputes the cheap local
//      phases (x-gather, k1, att1) in LDS, then computes its 56 att2 rows +
//      chunk softmax stats. ch==0 blocks additionally persist k1 for kC.
// kC : 50 blocks = (b,g). Combine stats, build window weights, v-conv + out.
#define BVO 28224   // 64*441 per-batch offset

// ws layout (floats):
//  k1g   [50][25][64]      80000
//  att2c [50][127][64]    406400   (att2 rows o2 in [157,284))
//  pm    [400][64]         25600
//  pz    [400][64]         25600

__global__ __launch_bounds__(256) void k1k(
    const float* __restrict__ x, const float* __restrict__ wk, const float* __restrict__ bk,
    const float* __restrict__ w1,
    const float* __restrict__ bn_gamma, const float* __restrict__ bn_beta,
    const float* __restrict__ bn_mean,  const float* __restrict__ bn_var,
    const float* __restrict__ w2, const float* __restrict__ b2,
    float* __restrict__ k1g, float* __restrict__ att2c,
    float* __restrict__ pm, float* __restrict__ pz)
{
    int blk = blockIdx.x;            // 400 = bg*8 + ch
    int ch = blk & 7, bg = blk >> 3;
    int b = bg / 25, g = bg % 25;
    int ph = g / 5, pw = g % 5;
    int tid = threadIdx.x, lane = tid & 63, wv = tid >> 6;

    __shared__ float xs[1600];       // xs[u], u = 25*c + p
    __shared__ float k1u[1600];      // k1u[u]
    __shared__ float att1[1600];     // [o][e]
    __shared__ float red[256];

    // A1: gather x at this (b,g)'s 25 pixels
    for (int u = tid; u < 1600; u += 256) {
        int c = u / 25, p = u - 25*c;
        int row = 5*(p/5) + ph, col = 5*(p%5) + pw;
        xs[u] = (row < 21 && col < 21) ? x[b*BVO + c*441 + row*21 + col] : 0.f;
    }
    __syncthreads();

    // A2: k1 at the 25 pixels (depthwise conv over channel axis)
    for (int k = 0; k < 7; ++k) {
        int p = wv + 4*k;
        if (p >= 25) break;                       // wave-uniform
        int row = 5*(p/5) + ph, col = 5*(p%5) + pw;
        float acc = 0.f;
        if (row < 21 && col < 21) {               // wave-uniform
            int d = row*21 + col;
            const float* wkp = wk + d*441 + 220 - lane;
            float a0 = 0.f, a1 = 0.f;
            #pragma unroll
            for (int cp = 0; cp < 64; cp += 2) {
                a0 += xs[25*cp + p]     * wkp[cp];
                a1 += xs[25*(cp+1) + p] * wkp[cp+1];
            }
            acc = bk[d] + a0 + a1;
        }
        k1u[lane*25 + p] = acc;                   // index = 25*c + p = u
        if (ch == 0) k1g[bg*1600 + p*64 + lane] = acc;
    }
    __syncthreads();

    // C: att1[o][e] = relu(BN(w1[g] @ kq)), kq column held in registers
    {
        float kq[50];
        #pragma unroll
        for (int m = 0; m < 25; ++m) kq[m] = xs[m*64 + lane];
        #pragma unroll
        for (int m = 0; m < 25; ++m) kq[25+m] = k1u[m*64 + lane];
        const float* w1g = w1 + g*1250;
        for (int k = 0; k < 7; ++k) {
            int o = wv + 4*k;
            if (o >= 25) break;                   // wave-uniform
            const float* wp = w1g + o*50;         // uniform -> s_loads
            float a0 = 0.f, a1 = 0.f;
            #pragma unroll
            for (int m = 0; m < 50; m += 2) { a0 += wp[m]*kq[m]; a1 += wp[m+1]*kq[m+1]; }
            float acc = a0 + a1;
            float inv = bn_gamma[g*25+o] * rsqrtf(bn_var[g*25+o] + 1e-5f);
            acc = (acc - bn_mean[g*25+o]) * inv + bn_beta[g*25+o];
            att1[o*64 + lane] = fmaxf(acc, 0.f);
        }
    }
    __syncthreads();

    // D: this chunk's 56 att2 rows + chunk softmax stats
    float a1r[25];
    #pragma unroll
    for (int i = 0; i < 25; ++i) a1r[i] = att1[i*64 + lane];

    int base = __builtin_amdgcn_readfirstlane(56*ch + 14*wv);   // 14 contiguous rows/wave
    const float* w2g = w2 + g*11025 + base*25;                  // uniform -> s_loads
    const float* b2g = b2 + g*441 + base;

    float vals[14];
    #pragma unroll
    for (int j = 0; j < 14; ++j) {
        int r = base + j;
        if (r < 441) {
            const float* wp = w2g + j*25;
            float a0 = 0.f, a1 = 0.f;
            #pragma unroll
            for (int i = 0; i < 24; i += 2) { a0 += wp[i]*a1r[i]; a1 += wp[i+1]*a1r[i+1]; }
            vals[j] = b2g[j] + a0 + a1 + wp[24]*a1r[24];
            if (r >= 157 && r < 284)
                att2c[(bg*127 + (r-157))*64 + lane] = vals[j];
        } else {
            vals[j] = -1e30f;
        }
    }

    float mx = vals[0];
    #pragma unroll
    for (int j = 1; j < 14; ++j) mx = fmaxf(mx, vals[j]);

    red[wv*64 + lane] = mx;
    __syncthreads();
    float M = fmaxf(fmaxf(red[0*64+lane], red[1*64+lane]),
                    fmaxf(red[2*64+lane], red[3*64+lane]));
    float z = 0.f;
    #pragma unroll
    for (int j = 0; j < 14; ++j) z += __expf(vals[j] - M);
    __syncthreads();
    red[wv*64 + lane] = z;
    __syncthreads();
    if (wv == 0) {
        float Z = red[0*64+lane] + red[1*64+lane] + red[2*64+lane] + red[3*64+lane];
        pm[blk*64 + lane] = M;
        pz[blk*64 + lane] = Z;
    }
}

__global__ __launch_bounds__(256) void kC(
    const float* __restrict__ x, const float* __restrict__ wvw, const float* __restrict__ bv,
    const float* __restrict__ k1g, const float* __restrict__ att2c,
    const float* __restrict__ pm, const float* __restrict__ pz,
    float* __restrict__ out)
{
    int blk = blockIdx.x;            // 50 = b*25+g
    int b = blk / 25, g = blk % 25;
    int ph = g / 5, pw = g % 5;
    int tid = threadIdx.x, lane = tid & 63, wv = tid >> 6;

    __shared__ float a2s[8128];      // att2 rows [157,284) x 64
    __shared__ float wT[4096];       // wT[cv][e]
    __shared__ float smM[64], smR[64];

    for (int i = tid; i < 8128; i += 256) a2s[i] = att2c[blk*8128 + i];
    if (tid < 64) {
        float M = -1e30f;
        #pragma unroll
        for (int c = 0; c < 8; ++c) M = fmaxf(M, pm[(blk*8 + c)*64 + tid]);
        float Z = 0.f;
        #pragma unroll
        for (int c = 0; c < 8; ++c)
            Z += pz[(blk*8 + c)*64 + tid] * __expf(pm[(blk*8 + c)*64 + tid] - M);
        smM[tid] = M;
        smR[tid] = 1.f / Z;
    }
    __syncthreads();

    // window weights: wT[cv][e] = exp(att2[cv+220-e][e] - M_e) / Z_e
    float Me = smM[lane], Re = smR[lane];
    #pragma unroll
    for (int k = 0; k < 16; ++k) {
        int cv = wv + 4*k;
        // diagonal read: addr = (cv+63-lane)*64 + lane -> bank = lane%32, conflict-free
        wT[cv*64 + lane] = __expf(a2s[(cv + 63 - lane)*64 + lane] - Me) * Re;
    }
    __syncthreads();

    // per pixel: depthwise 3x3 v-conv (lane = channel) + 64-wide dot + residual
    int y0 = (ph + 3) % 5, x0 = (pw + 3) % 5;
    int ny = (21 - y0 + 4) / 5, nx = (21 - x0 + 4) / 5;
    int npix = ny * nx;
    for (int k = 0; k < 7; ++k) {
        int p = wv + 4*k;
        if (p >= npix) break;                      // wave-uniform
        int yy = y0 + 5*(p / nx), xx = x0 + 5*(p % nx);
        float vt = 0.f;
        if (yy >= 2 && xx >= 2) {                  // wave-uniform
            int vy = yy - 2, vx = xx - 2;
            float vval = bv[lane];
            const float* xp = x + b*BVO + lane*441;
            #pragma unroll
            for (int ky = 0; ky < 3; ++ky) {
                int r2 = vy + ky - 1;
                if (r2 < 0 || r2 >= 21) continue;
                #pragma unroll
                for (int kx = 0; kx < 3; ++kx) {
                    int c2 = vx + kx - 1;
                    if (c2 < 0 || c2 >= 21) continue;
                    vval += xp[r2*21 + c2] * wvw[lane*9 + ky*3 + kx];
                }
            }
            #pragma unroll
            for (int cv = 0; cv < 64; ++cv) {
                float s = __uint_as_float(__builtin_amdgcn_readlane(__float_as_uint(vval), cv));
                vt += s * wT[cv*64 + lane];
            }
        }
        int pk = ((yy + 2 - ph) / 5) * 5 + ((xx + 2 - pw) / 5);
        float kt = k1g[blk*1600 + pk*64 + lane];
        out[b*BVO + lane*441 + yy*21 + xx] = kt + vt;
    }
}

extern "C" void kernel_launch(void* const* d_in, const int* in_sizes, int n_in,
                              void* d_out, int out_size, void* d_ws, size_t ws_size,
                              hipStream_t stream) {
    const float* x        = (const float*)d_in[0];
    const float* wk       = (const float*)d_in[1];
    const float* bk       = (const float*)d_in[2];
    const float* w1       = (const float*)d_in[3];
    const float* bn_gamma = (const float*)d_in[4];
    const float* bn_beta  = (const float*)d_in[5];
    const float* bn_mean  = (const float*)d_in[6];
    const float* bn_var   = (const float*)d_in[7];
    const float* w2       = (const float*)d_in[8];
    const float* b2       = (const float*)d_in[9];
    const float* wv       = (const float*)d_in[10];
    const float* bv       = (const float*)d_in[11];

    float* out   = (float*)d_out;
    float* k1g   = (float*)d_ws;        // 80000
    float* att2c = k1g + 80000;         // 406400
    float* pm    = att2c + 406400;      // 25600
    float* pz    = pm + 25600;          // 25600

    hipLaunchKernelGGL(k1k, dim3(400), dim3(256), 0, stream,
                       x, wk, bk, w1, bn_gamma, bn_beta, bn_mean, bn_var,
                       w2, b2, k1g, att2c, pm, pz);
    hipLaunchKernelGGL(kC, dim3(50), dim3(256), 0, stream,
                       x, wv, bv, k1g, att2c, pm, pz, out);
}